// Round 17
// baseline (678.262 us; speedup 1.0000x reference)
//
#include <hip/hip_runtime.h>
#include <hip/hip_bf16.h>
#include <math.h>

typedef __attribute__((ext_vector_type(8))) short short8;
typedef __attribute__((ext_vector_type(4))) short short4v;
typedef __attribute__((ext_vector_type(4))) float f32x4;

static __device__ __forceinline__ short f2bf(float f) {
  union { float f; unsigned u; } x;
  x.f = f;
  unsigned r = x.u + 0x7fffu + ((x.u >> 16) & 1u);
  return (short)(r >> 16);
}

#define GLD16(g, l)                                                   \
  __builtin_amdgcn_global_load_lds(                                   \
      (const __attribute__((address_space(1))) void*)(g),             \
      (__attribute__((address_space(3))) void*)(l), 16, 0, 0)
#define BAR() asm volatile("s_barrier" ::: "memory")
#define VMCNT0() asm volatile("s_waitcnt vmcnt(0)" ::: "memory")

// fused cast: x, Wq, Wk, Wv -> bf16 in one launch
__global__ __launch_bounds__(256) void cvt_all(
    const float* __restrict__ x, const float* __restrict__ wq,
    const float* __restrict__ wk, const float* __restrict__ wv,
    short* __restrict__ xb, short* __restrict__ wqb,
    short* __restrict__ wkb, short* __restrict__ wvb, int n0, int n1) {
  int i = blockIdx.x * 256 + threadIdx.x;
  const float* src; short* dst; int off;
  if (i < n0) { src = x; dst = xb; off = i; }
  else if (i < n0 + n1) { src = wq; dst = wqb; off = i - n0; }
  else if (i < n0 + 2 * n1) { src = wk; dst = wkb; off = i - n0 - n1; }
  else if (i < n0 + 3 * n1) { src = wv; dst = wvb; off = i - n0 - 2 * n1; }
  else return;
  const float4* p = (const float4*)src + (size_t)off * 2;
  float4 a = p[0], b = p[1];
  short8 o;
  o[0] = f2bf(a.x); o[1] = f2bf(a.y); o[2] = f2bf(a.z); o[3] = f2bf(a.w);
  o[4] = f2bf(b.x); o[5] = f2bf(b.y); o[6] = f2bf(b.z); o[7] = f2bf(b.w);
  *((short8*)dst + off) = o;
}

// ---------------------------------------------------------------------------
// C = A * B^T, bf16 MFMA 16x16x32. BM=256, BN=128, BK=32, 256 threads =
// 4 waves stacked in M; wave tile 64x128 (R13's proven best geometry:
// 42.7 FLOP/LDS-byte). NEW vs R13/R16: DOUBLE-buffered LDS (48 KB ->
// 3 blocks/CU = 12 waves/CU, __launch_bounds__(256,3)), distance-1 prefetch
// with vmcnt(0) per K-tile -- the m97 mechanism: per-wave exposed HBM
// latency is hidden by 3-block interleave (R13 had only 8 waves/CU; its
// 34% MfmaUtil vs the 45% LDS-BW ceiling is barrier/vmcnt stall that TLP
// can fill). Ledger: buf[t+1] free at iter-t barrier (iter t-1 ds_reads
// drained pre-MFMA pre-barrier); vmcnt(0) drains exactly tile t's 6 loads.
// Both-sides XOR swizzle (slot ^= (row>>1)&3), bijective XCD swizzle.
// MODE 2: C fp32 = acc*scale + rel_bias[gc-gr+ml-1] (scores)
// MODE 3: C fp32 = acc (PV)
// MODE 4: fused QKV: 1024-col slice 0 -> Q, 1 -> K, 2 -> V (ALL row-major)
// ---------------------------------------------------------------------------
template <int MODE>
__global__ __launch_bounds__(256, 3) void gemm_wt(
    const short* __restrict__ A, const short* __restrict__ Bt,
    void* __restrict__ C0, void* __restrict__ C1, void* __restrict__ C2,
    const float* __restrict__ rel_bias,
    int N, int K, long aZ, long bZ, long cZ, int Cdim, float scale, int ml) {
  __shared__ short sA[2][256 * 32];
  __shared__ short sB[2][128 * 32];
  const int tid = threadIdx.x, lane = tid & 63, wid = tid >> 6;

  // bijective XCD swizzle over the flat workgroup id
  const int gx = gridDim.x, gy = gridDim.y;
  const int nwg = gx * gy * (int)gridDim.z;
  const int f = ((int)blockIdx.z * gy + (int)blockIdx.y) * gx + (int)blockIdx.x;
  const int qq = nwg >> 3, rr = nwg & 7;
  const int xcd = f & 7, pos = f >> 3;
  const int lg = (xcd < rr ? xcd * (qq + 1) : rr * (qq + 1) + (xcd - rr) * qq) + pos;
  const int z = lg / (gx * gy);
  const int rem = lg - z * (gx * gy);
  const int bx = rem / gy, by = rem - bx * gy;  // by fastest: A-panel reuse

  const short* Az = A + (size_t)z * aZ;
  const short* Bz = Bt + (size_t)z * bZ;
  const int brow = bx * 256, bcol = by * 128;
  const int lrow = lane & 15, kg = lane >> 4;

  // staging: chunk c covers rows c*64..+63; thread -> row tid>>2, slot tid&3
  const int t4 = tid >> 2;
  const int logslot = (tid & 3) ^ ((tid >> 3) & 3);  // pre-swizzled src slot
  const short* aSrc[4];
#pragma unroll
  for (int c = 0; c < 4; ++c)
    aSrc[c] = Az + (size_t)(brow + c * 64 + t4) * K + logslot * 8;
  const short* bSrc[2];
#pragma unroll
  for (int c = 0; c < 2; ++c)
    bSrc[c] = Bz + (size_t)(bcol + c * 64 + t4) * K + logslot * 8;
  const int dW = wid * 512;  // wave-uniform LDS dest offset within chunk

  // ds_read: physical slot = kg ^ ((row>>1)&3); (row>>1)&3 == (lrow>>1)&3
  const int kOff = (kg ^ ((lrow >> 1) & 3)) * 8;
  const int aBase = (wid * 64 + lrow) * 32 + kOff;  // + m*512
  const int bBase = lrow * 32 + kOff;               // + n*512

  short8 a[4], b[8];
  f32x4 acc[4][8] = {};

  short *pa0 = &sA[0][0], *pa1 = &sA[1][0];
  short *pb0 = &sB[0][0], *pb1 = &sB[1][0];

#define STG(PA, PB, T)                                               \
  do {                                                               \
    GLD16(aSrc[0] + (size_t)(T) * 32, (PA) + 0 * 2048 + dW);         \
    GLD16(aSrc[1] + (size_t)(T) * 32, (PA) + 1 * 2048 + dW);         \
    GLD16(aSrc[2] + (size_t)(T) * 32, (PA) + 2 * 2048 + dW);         \
    GLD16(aSrc[3] + (size_t)(T) * 32, (PA) + 3 * 2048 + dW);         \
    GLD16(bSrc[0] + (size_t)(T) * 32, (PB) + 0 * 2048 + dW);         \
    GLD16(bSrc[1] + (size_t)(T) * 32, (PB) + 1 * 2048 + dW);         \
  } while (0)
#define RD(PA, PB)                                                  \
  do {                                                              \
    _Pragma("unroll") for (int m = 0; m < 4; ++m)                   \
        a[m] = *(const short8*)&(PA)[aBase + m * 512];              \
    _Pragma("unroll") for (int n = 0; n < 8; ++n)                   \
        b[n] = *(const short8*)&(PB)[bBase + n * 512];              \
  } while (0)
#define MFMA32()                                                              \
  do {                                                                        \
    __builtin_amdgcn_s_setprio(1);                                            \
    _Pragma("unroll") for (int m = 0; m < 4; ++m)                             \
        _Pragma("unroll") for (int n = 0; n < 8; ++n)                         \
            acc[m][n] = __builtin_amdgcn_mfma_f32_16x16x32_bf16(              \
                a[m], b[n], acc[m][n], 0, 0, 0);                              \
    __builtin_amdgcn_s_setprio(0);                                            \
  } while (0)
#define SWAP()                                                   \
  do {                                                           \
    short* q;                                                    \
    q = pa0; pa0 = pa1; pa1 = q;                                 \
    q = pb0; pb0 = pb1; pb1 = q;                                 \
  } while (0)

  // prologue: tile 0 staged (6 loads outstanding)
  STG(pa0, pb0, 0);

  const int NT = K >> 5;  // K/32 tiles (32 or 64 here)
  for (int t = 0; t < NT - 1; ++t) {
    VMCNT0();   // tile t landed
    BAR();      // all waves past reads of tile t-1 -> buf (t+1)&1 free
    RD(pa0, pb0);
    STG(pa1, pb1, t + 1);
    MFMA32();
    SWAP();
  }
  // t = NT-1: no staging
  VMCNT0();
  BAR();
  RD(pa0, pb0);
  MFMA32();

  // epilogue
#pragma unroll
  for (int m = 0; m < 4; ++m) {
#pragma unroll
    for (int n = 0; n < 8; ++n) {
#pragma unroll
      for (int r = 0; r < 4; ++r) {
        float v = acc[m][n][r];
        int gr = brow + wid * 64 + m * 16 + kg * 4 + r;
        int gc = bcol + n * 16 + lrow;
        if constexpr (MODE == 2) {
          int idx = gc - gr + (ml - 1);
          idx = min(max(idx, 0), 2 * ml - 2);
          ((float*)C0 + (size_t)z * cZ)[(size_t)gr * N + gc] =
              v * scale + rel_bias[idx];
        } else if constexpr (MODE == 3) {
          ((float*)C0 + (size_t)z * cZ)[(size_t)gr * N + gc] = v;
        } else {  // MODE 4: fused QKV, 1024-col slices, ALL row-major
          int s = gc >> 10, cc = gc & 1023;
          short* dst = (s == 0) ? (short*)C0 : (s == 1) ? (short*)C1 : (short*)C2;
          dst[(size_t)gr * 1024 + cc] = f2bf(v);
        }
      }
    }
  }
#undef STG
#undef RD
#undef MFMA32
#undef SWAP
}

// 64x64 LDS tile transpose: vin[b][c][e] (row-major [Cd][E]) -> vout[b][e][c]
__global__ __launch_bounds__(256) void transpose_v(const short* __restrict__ vin,
                                                   short* __restrict__ vout,
                                                   int Cd, int E) {
  __shared__ short t[64][72];
  const int c0 = blockIdx.x * 64, e0 = blockIdx.y * 64, b = blockIdx.z;
  const int tid = threadIdx.x;
  const int cr = tid >> 2;             // 0..63: input row within tile
  const int ec = (tid & 3) * 16;       // input col chunk
  const short* src = vin + ((size_t)b * Cd + c0 + cr) * E + e0 + ec;
  short8 v0 = *(const short8*)src;
  short8 v1 = *(const short8*)(src + 8);
#pragma unroll
  for (int j = 0; j < 8; ++j) t[ec + j][cr] = v0[j];
#pragma unroll
  for (int j = 0; j < 8; ++j) t[ec + 8 + j][cr] = v1[j];
  __syncthreads();
  const int er = tid >> 2;             // output row (e-dim)
  const int cc = (tid & 3) * 16;       // output col chunk (c-dim)
  short* dst = vout + ((size_t)b * E + e0 + er) * Cd + c0 + cc;
  *(short8*)dst = *(const short8*)&t[er][cc];
  *(short8*)(dst + 8) = *(const short8*)&t[er][cc + 8];
}

// Row softmax in place (rows of 2048) + bf16 copy for the PV GEMM.
__global__ __launch_bounds__(256) void softmax_rows(float* __restrict__ w,
                                                    short* __restrict__ wb, int Cd) {
  const size_t row = blockIdx.x;
  float4* p = (float4*)(w + row * (size_t)Cd);
  const int tid = threadIdx.x;
  float4 v0 = p[tid];
  float4 v1 = p[tid + 256];
  float mx = fmaxf(fmaxf(fmaxf(v0.x, v0.y), fmaxf(v0.z, v0.w)),
                   fmaxf(fmaxf(v1.x, v1.y), fmaxf(v1.z, v1.w)));
#pragma unroll
  for (int o = 32; o; o >>= 1) mx = fmaxf(mx, __shfl_xor(mx, o));
  __shared__ float red[8];
  const int wv = tid >> 6;
  if ((tid & 63) == 0) red[wv] = mx;
  __syncthreads();
  mx = fmaxf(fmaxf(red[0], red[1]), fmaxf(red[2], red[3]));
  v0.x = __expf(v0.x - mx); v0.y = __expf(v0.y - mx);
  v0.z = __expf(v0.z - mx); v0.w = __expf(v0.w - mx);
  v1.x = __expf(v1.x - mx); v1.y = __expf(v1.y - mx);
  v1.z = __expf(v1.z - mx); v1.w = __expf(v1.w - mx);
  float s = v0.x + v0.y + v0.z + v0.w + v1.x + v1.y + v1.z + v1.w;
#pragma unroll
  for (int o = 32; o; o >>= 1) s += __shfl_xor(s, o);
  if ((tid & 63) == 0) red[4 + wv] = s;
  __syncthreads();
  s = red[4] + red[5] + red[6] + red[7];
  float inv = 1.0f / s;
  v0.x *= inv; v0.y *= inv; v0.z *= inv; v0.w *= inv;
  v1.x *= inv; v1.y *= inv; v1.z *= inv; v1.w *= inv;
  p[tid] = v0;
  p[tid + 256] = v1;
  short4v b0, b1;
  b0[0] = f2bf(v0.x); b0[1] = f2bf(v0.y); b0[2] = f2bf(v0.z); b0[3] = f2bf(v0.w);
  b1[0] = f2bf(v1.x); b1[1] = f2bf(v1.y); b1[2] = f2bf(v1.z); b1[3] = f2bf(v1.w);
  short* wrow = wb + row * (size_t)Cd;
  *(short4v*)&wrow[tid * 4] = b0;
  *(short4v*)&wrow[1024 + tid * 4] = b1;
}

extern "C" void kernel_launch(void* const* d_in, const int* in_sizes, int n_in,
                              void* d_out, int out_size, void* d_ws, size_t ws_size,
                              hipStream_t stream) {
  const float* x = (const float*)d_in[0];
  const float* Wq = (const float*)d_in[1];
  const float* Wk = (const float*)d_in[2];
  const float* Wv = (const float*)d_in[3];
  const float* rb = (const float*)d_in[4];

  const int E = 1024;
  const int Mt = in_sizes[0] / E;           // B*C = 8192
  const int Cd = out_size / Mt - E;         // 2048
  const int B = Mt / Cd;                    // 4
  const int ml = (in_sizes[4] + 1) / 2;     // max_len = 2048
  const float scale = 1.0f / sqrtf((float)E);

  // workspace layout (bf16 = short), 70 MB
  short* xb = (short*)d_ws;                 // Mt*E (dead after QKV -> Vt)
  short* wqb = xb + (size_t)Mt * E;         // E*E x3
  short* wkb = wqb + (size_t)E * E;
  short* wvb = wkb + (size_t)E * E;
  short* Qb = wvb + (size_t)E * E;          // Mt*E
  short* Kb = Qb + (size_t)Mt * E;          // Mt*E
  short* Vrow = Kb + (size_t)Mt * E;        // Mt*E (V row-major)
  short* Vt = xb;                           // B*E*Cd = Mt*E (reuse xb)
  short* wbf = Qb;                          // Mt*Cd (reuse Q+K after scores)

  float* outp = (float*)d_out;              // Mt*E
  float* wts = outp + (size_t)Mt * E;       // Mt*Cd

  const int n0 = (Mt * E) / 8, n1 = (E * E) / 8;
  cvt_all<<<(n0 + 3 * n1 + 255) / 256, 256, 0, stream>>>(
      x, Wq, Wk, Wv, xb, wqb, wkb, wvb, n0, n1);

  dim3 blk(256);
  // fused QKV projection: A = xb (8192x1024), Bt = [Wq;Wk;Wv] (3072x1024)
  gemm_wt<4><<<dim3(Mt / 256, 3 * E / 128, 1), blk, 0, stream>>>(
      xb, wqb, Qb, Kb, Vrow, nullptr, 3 * E, E, 0, 0, 0, Cd, 0.f, ml);
  // scores = Q K^T * scale + bias (fp32 into weights region)
  gemm_wt<2><<<dim3(Cd / 256, Cd / 128, B), blk, 0, stream>>>(
      Qb, Kb, wts, nullptr, nullptr, rb, Cd, E, (long)Cd * E, (long)Cd * E,
      (long)Cd * Cd, Cd, scale, ml);
  softmax_rows<<<Mt, 256, 0, stream>>>(wts, wbf, Cd);
  // V -> V^T (xb region is dead now)
  transpose_v<<<dim3(Cd / 64, E / 64, B), 256, 0, stream>>>(Vrow, Vt, Cd, E);
  // out = weights @ V (A = bf16 weights, Bt = V^T)
  gemm_wt<3><<<dim3(Cd / 256, E / 128, B), blk, 0, stream>>>(
      wbf, Vt, outp, nullptr, nullptr, nullptr, E, Cd, (long)Cd * Cd,
      (long)E * Cd, (long)Cd * E, Cd, 0.f, ml);
}

// Round 18
// 193.787 us; speedup vs baseline: 3.5000x; 3.5000x over previous
//
#include <hip/hip_runtime.h>
#include <hip/hip_bf16.h>
#include <math.h>

typedef __attribute__((ext_vector_type(8))) short short8;
typedef __attribute__((ext_vector_type(4))) short short4v;
typedef __attribute__((ext_vector_type(4))) float f32x4;

static __device__ __forceinline__ short f2bf(float f) {
  union { float f; unsigned u; } x;
  x.f = f;
  unsigned r = x.u + 0x7fffu + ((x.u >> 16) & 1u);
  return (short)(r >> 16);
}

#define GLD16(g, l)                                                   \
  __builtin_amdgcn_global_load_lds(                                   \
      (const __attribute__((address_space(1))) void*)(g),             \
      (__attribute__((address_space(3))) void*)(l), 16, 0, 0)
#define BAR() asm volatile("s_barrier" ::: "memory")
#define VMCNT6() asm volatile("s_waitcnt vmcnt(6)" ::: "memory")
#define VMCNT0() asm volatile("s_waitcnt vmcnt(0)" ::: "memory")

// fused cast: x, Wq, Wk, Wv -> bf16 in one launch
__global__ __launch_bounds__(256) void cvt_all(
    const float* __restrict__ x, const float* __restrict__ wq,
    const float* __restrict__ wk, const float* __restrict__ wv,
    short* __restrict__ xb, short* __restrict__ wqb,
    short* __restrict__ wkb, short* __restrict__ wvb, int n0, int n1) {
  int i = blockIdx.x * 256 + threadIdx.x;
  const float* src; short* dst; int off;
  if (i < n0) { src = x; dst = xb; off = i; }
  else if (i < n0 + n1) { src = wq; dst = wqb; off = i - n0; }
  else if (i < n0 + 2 * n1) { src = wk; dst = wkb; off = i - n0 - n1; }
  else if (i < n0 + 3 * n1) { src = wv; dst = wvb; off = i - n0 - 2 * n1; }
  else return;
  const float4* p = (const float4*)src + (size_t)off * 2;
  float4 a = p[0], b = p[1];
  short8 o;
  o[0] = f2bf(a.x); o[1] = f2bf(a.y); o[2] = f2bf(a.z); o[3] = f2bf(a.w);
  o[4] = f2bf(b.x); o[5] = f2bf(b.y); o[6] = f2bf(b.z); o[7] = f2bf(b.w);
  *((short8*)dst + off) = o;
}

// ---------------------------------------------------------------------------
// C = A * B^T, bf16 MFMA 16x16x32. BM=256, BN=128, BK=32, 256 threads =
// 4 waves stacked in M; wave tile 64x128 (M_rep=4, N_rep=8). MEASURED BEST
// (193.8 us total, reproduced twice; QKV 63.3 us @ 34% MfmaUtil, no spill).
// TRIPLE-buffered LDS (72 KB -> 2 blocks/CU), rotating buffer pointers,
// one vmcnt(6) + one barrier per K-tile, distance-2 prefetch, both-sides
// XOR swizzle (slot ^= (row>>1)&3), bijective XCD block swizzle.
// OCCUPANCY NOTE (R17 failure): the unified VGPR/AGPR file needs ~250
// regs/wave here (acc[4][8]=128 not counted in VGPR_Count); bounds (256,3)
// spills the accumulator (WRITE 49->997 MB scratch). 2 blocks/CU is the
// hard cap for this geometry -- do not raise min-waves.
// MODE 2: C fp32 = acc*scale + rel_bias[gc-gr+ml-1] (scores)
// MODE 3: C fp32 = acc (PV)
// MODE 4: fused QKV: 1024-col slice 0 -> Q, 1 -> K, 2 -> V (ALL row-major)
// ---------------------------------------------------------------------------
template <int MODE>
__global__ __launch_bounds__(256, 2) void gemm_wt(
    const short* __restrict__ A, const short* __restrict__ Bt,
    void* __restrict__ C0, void* __restrict__ C1, void* __restrict__ C2,
    const float* __restrict__ rel_bias,
    int N, int K, long aZ, long bZ, long cZ, int Cdim, float scale, int ml) {
  __shared__ short sA[3][256 * 32];
  __shared__ short sB[3][128 * 32];
  const int tid = threadIdx.x, lane = tid & 63, wid = tid >> 6;

  // bijective XCD swizzle over the flat workgroup id
  const int gx = gridDim.x, gy = gridDim.y;
  const int nwg = gx * gy * (int)gridDim.z;
  const int f = ((int)blockIdx.z * gy + (int)blockIdx.y) * gx + (int)blockIdx.x;
  const int qq = nwg >> 3, rr = nwg & 7;
  const int xcd = f & 7, pos = f >> 3;
  const int lg = (xcd < rr ? xcd * (qq + 1) : rr * (qq + 1) + (xcd - rr) * qq) + pos;
  const int z = lg / (gx * gy);
  const int rem = lg - z * (gx * gy);
  const int bx = rem / gy, by = rem - bx * gy;  // by fastest: A-panel reuse

  const short* Az = A + (size_t)z * aZ;
  const short* Bz = Bt + (size_t)z * bZ;
  const int brow = bx * 256, bcol = by * 128;
  const int lrow = lane & 15, kg = lane >> 4;

  // staging: chunk c covers rows c*64..+63; thread -> row tid>>2, slot tid&3
  const int t4 = tid >> 2;
  const int logslot = (tid & 3) ^ ((tid >> 3) & 3);  // pre-swizzled src slot
  const short* aSrc[4];
#pragma unroll
  for (int c = 0; c < 4; ++c)
    aSrc[c] = Az + (size_t)(brow + c * 64 + t4) * K + logslot * 8;
  const short* bSrc[2];
#pragma unroll
  for (int c = 0; c < 2; ++c)
    bSrc[c] = Bz + (size_t)(bcol + c * 64 + t4) * K + logslot * 8;
  const int dW = wid * 512;  // wave-uniform LDS dest offset within chunk

  // ds_read: physical slot = kg ^ ((row>>1)&3); (row>>1)&3 == (lrow>>1)&3
  const int kOff = (kg ^ ((lrow >> 1) & 3)) * 8;
  const int aBase = (wid * 64 + lrow) * 32 + kOff;  // + m*512
  const int bBase = lrow * 32 + kOff;               // + n*512

  short8 a[4], b[8];
  f32x4 acc[4][8] = {};

  short *pa0 = &sA[0][0], *pa1 = &sA[1][0], *pa2 = &sA[2][0];
  short *pb0 = &sB[0][0], *pb1 = &sB[1][0], *pb2 = &sB[2][0];

#define STG(PA, PB, T)                                               \
  do {                                                               \
    GLD16(aSrc[0] + (size_t)(T) * 32, (PA) + 0 * 2048 + dW);         \
    GLD16(aSrc[1] + (size_t)(T) * 32, (PA) + 1 * 2048 + dW);         \
    GLD16(aSrc[2] + (size_t)(T) * 32, (PA) + 2 * 2048 + dW);         \
    GLD16(aSrc[3] + (size_t)(T) * 32, (PA) + 3 * 2048 + dW);         \
    GLD16(bSrc[0] + (size_t)(T) * 32, (PB) + 0 * 2048 + dW);         \
    GLD16(bSrc[1] + (size_t)(T) * 32, (PB) + 1 * 2048 + dW);         \
  } while (0)
#define RD(PA, PB)                                                  \
  do {                                                              \
    _Pragma("unroll") for (int m = 0; m < 4; ++m)                   \
        a[m] = *(const short8*)&(PA)[aBase + m * 512];              \
    _Pragma("unroll") for (int n = 0; n < 8; ++n)                   \
        b[n] = *(const short8*)&(PB)[bBase + n * 512];              \
  } while (0)
#define MFMA32()                                                              \
  do {                                                                        \
    __builtin_amdgcn_s_setprio(1);                                            \
    _Pragma("unroll") for (int m = 0; m < 4; ++m)                             \
        _Pragma("unroll") for (int n = 0; n < 8; ++n)                         \
            acc[m][n] = __builtin_amdgcn_mfma_f32_16x16x32_bf16(              \
                a[m], b[n], acc[m][n], 0, 0, 0);                              \
    __builtin_amdgcn_s_setprio(0);                                            \
  } while (0)
#define ROT()                                                    \
  do {                                                           \
    short* q;                                                    \
    q = pa0; pa0 = pa1; pa1 = pa2; pa2 = q;                      \
    q = pb0; pb0 = pb1; pb1 = pb2; pb2 = q;                      \
  } while (0)

  // prologue: tiles 0,1 staged (12 loads outstanding)
  STG(pa0, pb0, 0);
  STG(pa1, pb1, 1);

  const int NT = K >> 5;  // K/32 tiles (32 or 64 here)
  for (int t = 0; t < NT - 2; ++t) {
    VMCNT6();   // drain tile t (tile t+1's 6 stay in flight)
    BAR();
    RD(pa0, pb0);
    STG(pa2, pb2, t + 2);   // buf freed by iter t-1's reads (pre-barrier)
    MFMA32();
    ROT();
  }
  // t = NT-2: no staging
  VMCNT6();
  BAR();
  RD(pa0, pb0);
  MFMA32();
  ROT();
  // t = NT-1
  VMCNT0();
  BAR();
  RD(pa0, pb0);
  MFMA32();

  // epilogue
#pragma unroll
  for (int m = 0; m < 4; ++m) {
#pragma unroll
    for (int n = 0; n < 8; ++n) {
#pragma unroll
      for (int r = 0; r < 4; ++r) {
        float v = acc[m][n][r];
        int gr = brow + wid * 64 + m * 16 + kg * 4 + r;
        int gc = bcol + n * 16 + lrow;
        if constexpr (MODE == 2) {
          int idx = gc - gr + (ml - 1);
          idx = min(max(idx, 0), 2 * ml - 2);
          ((float*)C0 + (size_t)z * cZ)[(size_t)gr * N + gc] =
              v * scale + rel_bias[idx];
        } else if constexpr (MODE == 3) {
          ((float*)C0 + (size_t)z * cZ)[(size_t)gr * N + gc] = v;
        } else {  // MODE 4: fused QKV, 1024-col slices, ALL row-major
          int s = gc >> 10, cc = gc & 1023;
          short* dst = (s == 0) ? (short*)C0 : (s == 1) ? (short*)C1 : (short*)C2;
          dst[(size_t)gr * 1024 + cc] = f2bf(v);
        }
      }
    }
  }
#undef STG
#undef RD
#undef MFMA32
#undef ROT
}

// 64x64 LDS tile transpose: vin[b][c][e] (row-major [Cd][E]) -> vout[b][e][c]
__global__ __launch_bounds__(256) void transpose_v(const short* __restrict__ vin,
                                                   short* __restrict__ vout,
                                                   int Cd, int E) {
  __shared__ short t[64][72];
  const int c0 = blockIdx.x * 64, e0 = blockIdx.y * 64, b = blockIdx.z;
  const int tid = threadIdx.x;
  const int cr = tid >> 2;             // 0..63: input row within tile
  const int ec = (tid & 3) * 16;       // input col chunk
  const short* src = vin + ((size_t)b * Cd + c0 + cr) * E + e0 + ec;
  short8 v0 = *(const short8*)src;
  short8 v1 = *(const short8*)(src + 8);
#pragma unroll
  for (int j = 0; j < 8; ++j) t[ec + j][cr] = v0[j];
#pragma unroll
  for (int j = 0; j < 8; ++j) t[ec + 8 + j][cr] = v1[j];
  __syncthreads();
  const int er = tid >> 2;             // output row (e-dim)
  const int cc = (tid & 3) * 16;       // output col chunk (c-dim)
  short* dst = vout + ((size_t)b * E + e0 + er) * Cd + c0 + cc;
  *(short8*)dst = *(const short8*)&t[er][cc];
  *(short8*)(dst + 8) = *(const short8*)&t[er][cc + 8];
}

// Row softmax in place (rows of 2048) + bf16 copy for the PV GEMM.
__global__ __launch_bounds__(256) void softmax_rows(float* __restrict__ w,
                                                    short* __restrict__ wb, int Cd) {
  const size_t row = blockIdx.x;
  float4* p = (float4*)(w + row * (size_t)Cd);
  const int tid = threadIdx.x;
  float4 v0 = p[tid];
  float4 v1 = p[tid + 256];
  float mx = fmaxf(fmaxf(fmaxf(v0.x, v0.y), fmaxf(v0.z, v0.w)),
                   fmaxf(fmaxf(v1.x, v1.y), fmaxf(v1.z, v1.w)));
#pragma unroll
  for (int o = 32; o; o >>= 1) mx = fmaxf(mx, __shfl_xor(mx, o));
  __shared__ float red[8];
  const int wv = tid >> 6;
  if ((tid & 63) == 0) red[wv] = mx;
  __syncthreads();
  mx = fmaxf(fmaxf(red[0], red[1]), fmaxf(red[2], red[3]));
  v0.x = __expf(v0.x - mx); v0.y = __expf(v0.y - mx);
  v0.z = __expf(v0.z - mx); v0.w = __expf(v0.w - mx);
  v1.x = __expf(v1.x - mx); v1.y = __expf(v1.y - mx);
  v1.z = __expf(v1.z - mx); v1.w = __expf(v1.w - mx);
  float s = v0.x + v0.y + v0.z + v0.w + v1.x + v1.y + v1.z + v1.w;
#pragma unroll
  for (int o = 32; o; o >>= 1) s += __shfl_xor(s, o);
  if ((tid & 63) == 0) red[4 + wv] = s;
  __syncthreads();
  s = red[4] + red[5] + red[6] + red[7];
  float inv = 1.0f / s;
  v0.x *= inv; v0.y *= inv; v0.z *= inv; v0.w *= inv;
  v1.x *= inv; v1.y *= inv; v1.z *= inv; v1.w *= inv;
  p[tid] = v0;
  p[tid + 256] = v1;
  short4v b0, b1;
  b0[0] = f2bf(v0.x); b0[1] = f2bf(v0.y); b0[2] = f2bf(v0.z); b0[3] = f2bf(v0.w);
  b1[0] = f2bf(v1.x); b1[1] = f2bf(v1.y); b1[2] = f2bf(v1.z); b1[3] = f2bf(v1.w);
  short* wrow = wb + row * (size_t)Cd;
  *(short4v*)&wrow[tid * 4] = b0;
  *(short4v*)&wrow[1024 + tid * 4] = b1;
}

extern "C" void kernel_launch(void* const* d_in, const int* in_sizes, int n_in,
                              void* d_out, int out_size, void* d_ws, size_t ws_size,
                              hipStream_t stream) {
  const float* x = (const float*)d_in[0];
  const float* Wq = (const float*)d_in[1];
  const float* Wk = (const float*)d_in[2];
  const float* Wv = (const float*)d_in[3];
  const float* rb = (const float*)d_in[4];

  const int E = 1024;
  const int Mt = in_sizes[0] / E;           // B*C = 8192
  const int Cd = out_size / Mt - E;         // 2048
  const int B = Mt / Cd;                    // 4
  const int ml = (in_sizes[4] + 1) / 2;     // max_len = 2048
  const float scale = 1.0f / sqrtf((float)E);

  // workspace layout (bf16 = short), 70 MB
  short* xb = (short*)d_ws;                 // Mt*E (dead after QKV -> Vt)
  short* wqb = xb + (size_t)Mt * E;         // E*E x3
  short* wkb = wqb + (size_t)E * E;
  short* wvb = wkb + (size_t)E * E;
  short* Qb = wvb + (size_t)E * E;          // Mt*E
  short* Kb = Qb + (size_t)Mt * E;          // Mt*E
  short* Vrow = Kb + (size_t)Mt * E;        // Mt*E (V row-major)
  short* Vt = xb;                           // B*E*Cd = Mt*E (reuse xb)
  short* wbf = Qb;                          // Mt*Cd (reuse Q+K after scores)

  float* outp = (float*)d_out;              // Mt*E
  float* wts = outp + (size_t)Mt * E;       // Mt*Cd

  const int n0 = (Mt * E) / 8, n1 = (E * E) / 8;
  cvt_all<<<(n0 + 3 * n1 + 255) / 256, 256, 0, stream>>>(
      x, Wq, Wk, Wv, xb, wqb, wkb, wvb, n0, n1);

  dim3 blk(256);
  // fused QKV projection: A = xb (8192x1024), Bt = [Wq;Wk;Wv] (3072x1024)
  gemm_wt<4><<<dim3(Mt / 256, 3 * E / 128, 1), blk, 0, stream>>>(
      xb, wqb, Qb, Kb, Vrow, nullptr, 3 * E, E, 0, 0, 0, Cd, 0.f, ml);
  // scores = Q K^T * scale + bias (fp32 into weights region)
  gemm_wt<2><<<dim3(Cd / 256, Cd / 128, B), blk, 0, stream>>>(
      Qb, Kb, wts, nullptr, nullptr, rb, Cd, E, (long)Cd * E, (long)Cd * E,
      (long)Cd * Cd, Cd, scale, ml);
  softmax_rows<<<Mt, 256, 0, stream>>>(wts, wbf, Cd);
  // V -> V^T (xb region is dead now)
  transpose_v<<<dim3(Cd / 64, E / 64, B), 256, 0, stream>>>(Vrow, Vt, Cd, E);
  // out = weights @ V (A = bf16 weights, Bt = V^T)
  gemm_wt<3><<<dim3(Cd / 256, E / 128, B), blk, 0, stream>>>(
      wbf, Vt, outp, nullptr, nullptr, nullptr, E, Cd, (long)Cd * Cd,
      (long)E * Cd, (long)Cd * E, Cd, 0.f, ml);
}